// Round 2
// baseline (253.769 us; speedup 1.0000x reference)
//
#include <hip/hip_runtime.h>
#include <math.h>

#define BB 64
#define FF 256
#define FQ 64              // FF/4
#define CC 100000
#define TSCALE 1.0f
#define PMARG 0.2f
#define NMARG 0.3f
#define GBLK 391           // ceil(CC/256)
#define WS_GRAM_OFF (GBLK * 64)   // float offset of Gram matrix in ws

__device__ __forceinline__ float wredf(float v) {
#pragma unroll
    for (int s = 1; s < 64; s <<= 1) v += __shfl_xor(v, s, 64);
    return v;
}

// blocks 0..GBLK-1: 256 columns each, 1 col/thread, 64-row acc in VGPRs.
// A (inputs) is read with wave-UNIFORM addresses -> compiler scalarizes to
// s_load (SMEM pipe), freeing LDS entirely (R1 was LDS-throughput-bound).
// block GBLK: Gram matrix G = inputs @ inputs.T -> ws[WS_GRAM_OFF..]
__global__ __launch_bounds__(256) void k_gemm(const float* __restrict__ in,
                                              const float* __restrict__ V,
                                              float* __restrict__ logits,
                                              float* __restrict__ ws) {
    __shared__ float sW[4 * 64];
    int tid = threadIdx.x;
    const float4* __restrict__ in4 = (const float4*)in;

    if (blockIdx.x == GBLK) {
        // ---- Gram block: 4x4 register tile per thread, reads A from global ----
        int r0 = (tid >> 4) << 2;
        int c0 = (tid & 15) << 2;
        float g[4][4];
#pragma unroll
        for (int r = 0; r < 4; ++r)
#pragma unroll
            for (int c = 0; c < 4; ++c) g[r][c] = 0.f;
        for (int kq = 0; kq < FQ; ++kq) {
            float4 a[4], b[4];
#pragma unroll
            for (int r = 0; r < 4; ++r) a[r] = in4[(r0 + r) * FQ + kq];
#pragma unroll
            for (int c = 0; c < 4; ++c) b[c] = in4[(c0 + c) * FQ + kq];
#pragma unroll
            for (int r = 0; r < 4; ++r)
#pragma unroll
                for (int c = 0; c < 4; ++c)
                    g[r][c] += a[r].x * b[c].x + a[r].y * b[c].y +
                               a[r].z * b[c].z + a[r].w * b[c].w;
        }
        float* G = ws + WS_GRAM_OFF;
#pragma unroll
        for (int r = 0; r < 4; ++r)
#pragma unroll
            for (int c = 0; c < 4; ++c)
                G[(r0 + r) * 64 + (c0 + c)] = g[r][c];
        return;
    }

    // ---- GEMM block ----
    int c = blockIdx.x * 256 + tid;
    bool valid = c < CC;
    int cidx = valid ? c : 0;
    const float4* __restrict__ Vp = (const float4*)(V + (size_t)cidx * FF);
    float acc[64];
#pragma unroll
    for (int m = 0; m < 64; ++m) acc[m] = 0.f;
    for (int kq = 0; kq < FQ; ++kq) {
        float4 v = Vp[kq];
#pragma unroll
        for (int m = 0; m < 64; ++m) {
            float4 s = in4[m * FQ + kq];   // uniform address -> s_load (SMEM)
            acc[m] = fmaf(s.x, v.x, acc[m]);
            acc[m] = fmaf(s.y, v.y, acc[m]);
            acc[m] = fmaf(s.z, v.z, acc[m]);
            acc[m] = fmaf(s.w, v.w, acc[m]);
        }
    }
    // write logits (coalesced per m across lanes) + exp for fused logsumexp
#pragma unroll
    for (int m = 0; m < 64; ++m) {
        float lg = acc[m] * TSCALE;
        if (valid) logits[(size_t)m * CC + c] = lg;
        acc[m] = valid ? expf(lg) : 0.f;   // |lg| <= ~19 -> no overflow in f32
    }
    // per-row sum of exp across this block's 256 columns:
    // butterfly-reduce each row over the wave, lane m keeps row m's sum
    int lane = tid & 63;
    int w = tid >> 6;
    float keep = 0.f;
#pragma unroll
    for (int m = 0; m < 64; ++m) {
        float r = wredf(acc[m]);
        if (lane == m) keep = r;
    }
    sW[w * 64 + lane] = keep;
    __syncthreads();
    if (tid < 64) {
        float t = sW[tid] + sW[64 + tid] + sW[128 + tid] + sW[192 + tid];
        ws[(size_t)blockIdx.x * 64 + tid] = t;   // deterministic partial, no atomics
    }
}

__device__ __forceinline__ bool mask_at(const void* p, int idx, int mode) {
    if (mode == 0) return ((const int*)p)[idx] != 0;
    if (mode == 1) return ((const float*)p)[idx] != 0.f;
    return ((const unsigned char*)p)[idx] != 0;
}

// one wave: combine logsumexp partials, bu_loss, sims from Gram, hp/hn losses
__global__ __launch_bounds__(64) void k_final(const int* __restrict__ targets,
                                              const void* __restrict__ pmask,
                                              const void* __restrict__ nmask,
                                              const float* __restrict__ logits,
                                              const float* __restrict__ ws,
                                              float* __restrict__ out) {
    int lane = threadIdx.x;   // 0..63 == batch row

    // detect mask storage layout: int32 (0/1 words), float32 (0/1.0f), or uint8
    const unsigned int* pw = (const unsigned int*)pmask;
    int okInt = 1, okFlt = 1;
#pragma unroll
    for (int i = 0; i < 16; ++i) {
        unsigned int wv = pw[lane * 16 + i];   // first 4KB, safe for all layouts
        okInt = okInt && (wv <= 1u);
        okFlt = okFlt && (wv == 0u || wv == 0x3f800000u);
    }
    int mode = __all(okInt) ? 0 : (__all(okFlt) ? 1 : 2);

    // bu_loss pieces
    float se = 0.f;
    for (int b = 0; b < GBLK; ++b) se += ws[b * 64 + lane];
    float lse = logf(se);
    int tgt = targets[lane];
    float nll = lse - logits[(size_t)lane * CC + tgt];

    // sims row from Gram
    const float* G = ws + WS_GRAM_OFF;
    float rinv = rsqrtf(G[lane * 64 + lane]);

    float minp = INFINITY, maxthd = -INFINITY;
    for (int j = 0; j < 64; ++j) {
        float rj = __shfl(rinv, j, 64);      // uniform loop, shfl before divergence
        float sim = G[lane * 64 + j] * rinv * rj;
        sim = fminf(1.f, fmaxf(-1.f, sim));
        if (j != lane) {
            bool pm = mask_at(pmask, lane * 64 + j, mode);
            float ps = pm ? sim : 2.0f;
            minp = fminf(minp, ps);
            maxthd = fmaxf(maxthd, pm ? sim : -2.0f);  // thd: sentinel 2.0 -> -2.0
        }
    }
    float n_thrd = minp - NMARG;
    float p_thrd = maxthd - PMARG;

    float hps = 0.f, hns = 0.f, hpc = 0.f, hnc = 0.f;
    for (int j = 0; j < 64; ++j) {
        float rj = __shfl(rinv, j, 64);
        float sim = G[lane * 64 + j] * rinv * rj;
        sim = fminf(1.f, fmaxf(-1.f, sim));
        if (j != lane) {
            bool pm = mask_at(pmask, lane * 64 + j, mode);
            bool nm = mask_at(nmask, lane * 64 + j, mode);
            float ps = pm ? sim : 2.0f;
            float ns = nm ? sim : 2.0f;
            if (ps < p_thrd) { hps += log1pf(expf(-ps)); hpc += 1.f; }
            if (ns < n_thrd) { hns += log1pf(expf(-ns)); hnc += 1.f; }
        }
    }

    float snll = wredf(nll);
    float shps = wredf(hps);
    float shns = wredf(hns);
    float shpc = wredf(hpc);
    float shnc = wredf(hnc);
    if (lane == 0) {
        float bu = snll * (1.f / 64.f);
        float hp = shpc > 0.f ? shps / shpc : 0.f;
        float hn = shnc > 0.f ? shns / shnc : 0.f;
        out[0] = bu + hp + hn;
    }
}

extern "C" void kernel_launch(void* const* d_in, const int* in_sizes, int n_in,
                              void* d_out, int out_size, void* d_ws, size_t ws_size,
                              hipStream_t stream) {
    const float* inputs = (const float*)d_in[0];
    const int* targets  = (const int*)d_in[1];
    const void* pmask   = d_in[2];
    const void* nmask   = d_in[3];
    const float* V      = (const float*)d_in[4];
    float* out = (float*)d_out;      // out[0] = loss
    float* logits = out + 1;         // out[1..] = logits [64][100000] row-major
    float* ws = (float*)d_ws;        // [GBLK*64] exp partials | [64*64] Gram

    hipLaunchKernelGGL(k_gemm, dim3(GBLK + 1), dim3(256), 0, stream,
                       inputs, V, logits, ws);
    hipLaunchKernelGGL(k_final, dim3(1), dim3(64), 0, stream,
                       targets, pmask, nmask, logits, ws, out);
}

// Round 3
// 122.678 us; speedup vs baseline: 2.0686x; 2.0686x over previous
//
#include <hip/hip_runtime.h>
#include <math.h>

#define BB 64
#define FF 256
#define CC 100000
#define TSCALE 1.0f
#define PMARG 0.2f
#define NMARG 0.3f
#define GBLK 391                  // 391 blocks x 256 cols = 100096 >= CC
#define WS_GRAM_OFF (GBLK * 64)   // float offset of Gram matrix in ws

typedef __attribute__((ext_vector_type(8))) short short8;   // 8 bf16 = 4 VGPR
typedef __attribute__((ext_vector_type(4))) float f32x4;

__device__ __forceinline__ float wredf(float v) {
#pragma unroll
    for (int s = 1; s < 64; s <<= 1) v += __shfl_xor(v, s, 64);
    return v;
}

// f32 -> bf16 round-to-nearest-even, bit math (no __bf16 dependency)
__device__ __forceinline__ short f2bf(float f) {
    unsigned u = __float_as_uint(f);
    unsigned r = (u + 0x7fffu + ((u >> 16) & 1u)) >> 16;
    return (short)r;
}
__device__ __forceinline__ short8 pack8(float4 a, float4 b) {
    short8 o;
    o[0] = f2bf(a.x); o[1] = f2bf(a.y); o[2] = f2bf(a.z); o[3] = f2bf(a.w);
    o[4] = f2bf(b.x); o[5] = f2bf(b.y); o[6] = f2bf(b.z); o[7] = f2bf(b.w);
    return o;
}

// blocks 0..GBLK-1: bf16 MFMA GEMM. Per block: 256 cols; per wave: 64 cols
// (4 tiles of 16), all 64 rows. A kept in VGPR fragments (no LDS pipe).
// block GBLK: Gram matrix G = inputs @ inputs.T -> ws[WS_GRAM_OFF..]
__global__ __launch_bounds__(256, 2) void k_gemm(const float* __restrict__ in,
                                                 const float* __restrict__ V,
                                                 float* __restrict__ logits,
                                                 float* __restrict__ ws) {
    __shared__ float sW[4 * 64];
    int tid = threadIdx.x;
    const float4* __restrict__ in4 = (const float4*)in;

    if (blockIdx.x == GBLK) {
        // ---- Gram block: 4x4 register tile per thread, f32 (needs accuracy) ----
        int r0 = (tid >> 4) << 2;
        int c0 = (tid & 15) << 2;
        float gacc[4][4];
#pragma unroll
        for (int r = 0; r < 4; ++r)
#pragma unroll
            for (int c = 0; c < 4; ++c) gacc[r][c] = 0.f;
        for (int kq = 0; kq < 64; ++kq) {
            float4 a[4], b[4];
#pragma unroll
            for (int r = 0; r < 4; ++r) a[r] = in4[(r0 + r) * 64 + kq];
#pragma unroll
            for (int c = 0; c < 4; ++c) b[c] = in4[(c0 + c) * 64 + kq];
#pragma unroll
            for (int r = 0; r < 4; ++r)
#pragma unroll
                for (int c = 0; c < 4; ++c)
                    gacc[r][c] += a[r].x * b[c].x + a[r].y * b[c].y +
                                  a[r].z * b[c].z + a[r].w * b[c].w;
        }
        float* G = ws + WS_GRAM_OFF;
#pragma unroll
        for (int r = 0; r < 4; ++r)
#pragma unroll
            for (int c = 0; c < 4; ++c)
                G[(r0 + r) * 64 + (c0 + c)] = gacc[r][c];
        return;
    }

    int lane = tid & 63, w = tid >> 6;
    int g = lane >> 4, c4 = lane & 15;
    int col0 = blockIdx.x * 256 + w * 64;

    // ---- A prologue: 32 fragments (4 M-tiles x 8 k-steps), 8 contiguous k/lane
    // fragment layout for mfma_f32_16x16x32_bf16: row = lane&15, k = (lane>>4)*8+j
    short8 afrag[4][8];            // 128 VGPRs
#pragma unroll
    for (int mt = 0; mt < 4; ++mt)
#pragma unroll
        for (int ks = 0; ks < 8; ++ks) {
            int base = (mt * 16 + c4) * 64 + ks * 8 + g * 2;
            afrag[mt][ks] = pack8(in4[base], in4[base + 1]);
        }

    float sums[4][4];              // running exp-sums, 16 VGPRs
#pragma unroll
    for (int mt = 0; mt < 4; ++mt)
#pragma unroll
        for (int r = 0; r < 4; ++r) sums[mt][r] = 0.f;

    for (int t = 0; t < 4; ++t) {
        int colB = col0 + t * 16 + c4;
        int cc = colB < CC ? colB : CC - 1;
        // per-lane V row pointer; k-step offsets become immediates
        const float4* __restrict__ vp = (const float4*)(V + (size_t)cc * FF) + g * 2;

        f32x4 acc0 = {0.f, 0.f, 0.f, 0.f};
        f32x4 acc1 = {0.f, 0.f, 0.f, 0.f};
        f32x4 acc2 = {0.f, 0.f, 0.f, 0.f};
        f32x4 acc3 = {0.f, 0.f, 0.f, 0.f};
#pragma unroll
        for (int ks = 0; ks < 8; ++ks) {
            float4 b0 = vp[ks * 8];
            float4 b1 = vp[ks * 8 + 1];
            short8 bf = pack8(b0, b1);
            acc0 = __builtin_amdgcn_mfma_f32_16x16x32_bf16(afrag[0][ks], bf, acc0, 0, 0, 0);
            acc1 = __builtin_amdgcn_mfma_f32_16x16x32_bf16(afrag[1][ks], bf, acc1, 0, 0, 0);
            acc2 = __builtin_amdgcn_mfma_f32_16x16x32_bf16(afrag[2][ks], bf, acc2, 0, 0, 0);
            acc3 = __builtin_amdgcn_mfma_f32_16x16x32_bf16(afrag[3][ks], bf, acc3, 0, 0, 0);
        }

        bool cv = colB < CC;
        // C/D layout: col = lane&15 (= colB), row = mt*16 + (lane>>4)*4 + reg
#pragma unroll
        for (int mt = 0; mt < 4; ++mt) {
            f32x4 a = (mt == 0) ? acc0 : (mt == 1) ? acc1 : (mt == 2) ? acc2 : acc3;
#pragma unroll
            for (int r = 0; r < 4; ++r) {
                float lg = a[r] * TSCALE;
                if (cv) logits[(size_t)(mt * 16 + g * 4 + r) * CC + colB] = lg;
                sums[mt][r] += cv ? expf(lg) : 0.f;   // |lg| <= ~19, no overflow
            }
        }
    }

    // reduce exp-sums across the 16 cols of each row (lanes within 16-lane group)
#pragma unroll
    for (int mt = 0; mt < 4; ++mt)
#pragma unroll
        for (int r = 0; r < 4; ++r) {
            float s = sums[mt][r];
            s += __shfl_xor(s, 1, 64);
            s += __shfl_xor(s, 2, 64);
            s += __shfl_xor(s, 4, 64);
            s += __shfl_xor(s, 8, 64);
            if (c4 == 0) sW[w * 64 + mt * 16 + g * 4 + r] = s;
        }
    __syncthreads();
    if (tid < 64) {
        float tsum = sW[tid] + sW[64 + tid] + sW[128 + tid] + sW[192 + tid];
        ws[(size_t)blockIdx.x * 64 + tid] = tsum;   // deterministic, no atomics
    }
}

__device__ __forceinline__ bool mask_at(const void* p, int idx, int mode) {
    if (mode == 0) return ((const int*)p)[idx] != 0;
    if (mode == 1) return ((const float*)p)[idx] != 0.f;
    return ((const unsigned char*)p)[idx] != 0;
}

// 256 threads: parallel logsumexp-combine, then wave 0 does the scalar tail
__global__ __launch_bounds__(256) void k_final(const int* __restrict__ targets,
                                               const void* __restrict__ pmask,
                                               const void* __restrict__ nmask,
                                               const float* __restrict__ logits,
                                               const float* __restrict__ ws,
                                               float* __restrict__ out) {
    __shared__ float sSe[256];
    int tid = threadIdx.x;
    {
        int row = tid & 63, part = tid >> 6;
        float se = 0.f;
        for (int b = part; b < GBLK; b += 4) se += ws[b * 64 + row];
        sSe[tid] = se;
    }
    __syncthreads();
    if (tid >= 64) return;

    int lane = tid;   // 0..63 == batch row
    float se = sSe[lane] + sSe[64 + lane] + sSe[128 + lane] + sSe[192 + lane];

    // detect mask storage layout: int32 (0/1 words), float32 (0/1.0f), or uint8
    const unsigned int* pw = (const unsigned int*)pmask;
    int okInt = 1, okFlt = 1;
#pragma unroll
    for (int i = 0; i < 16; ++i) {
        unsigned int wv = pw[lane * 16 + i];
        okInt = okInt && (wv <= 1u);
        okFlt = okFlt && (wv == 0u || wv == 0x3f800000u);
    }
    int mode = __all(okInt) ? 0 : (__all(okFlt) ? 1 : 2);

    float lse = logf(se);
    int tgt = targets[lane];
    float nll = lse - logits[(size_t)lane * CC + tgt];

    const float* G = ws + WS_GRAM_OFF;
    float rinv = rsqrtf(G[lane * 64 + lane]);

    float minp = INFINITY, maxthd = -INFINITY;
    for (int j = 0; j < 64; ++j) {
        float rj = __shfl(rinv, j, 64);
        float sim = G[lane * 64 + j] * rinv * rj;
        sim = fminf(1.f, fmaxf(-1.f, sim));
        if (j != lane) {
            bool pm = mask_at(pmask, lane * 64 + j, mode);
            float ps = pm ? sim : 2.0f;
            minp = fminf(minp, ps);
            maxthd = fmaxf(maxthd, pm ? sim : -2.0f);
        }
    }
    float n_thrd = minp - NMARG;
    float p_thrd = maxthd - PMARG;

    float hps = 0.f, hns = 0.f, hpc = 0.f, hnc = 0.f;
    for (int j = 0; j < 64; ++j) {
        float rj = __shfl(rinv, j, 64);
        float sim = G[lane * 64 + j] * rinv * rj;
        sim = fminf(1.f, fmaxf(-1.f, sim));
        if (j != lane) {
            bool pm = mask_at(pmask, lane * 64 + j, mode);
            bool nm = mask_at(nmask, lane * 64 + j, mode);
            float ps = pm ? sim : 2.0f;
            float ns = nm ? sim : 2.0f;
            if (ps < p_thrd) { hps += log1pf(expf(-ps)); hpc += 1.f; }
            if (ns < n_thrd) { hns += log1pf(expf(-ns)); hnc += 1.f; }
        }
    }

    float snll = wredf(nll);
    float shps = wredf(hps);
    float shns = wredf(hns);
    float shpc = wredf(hpc);
    float shnc = wredf(hnc);
    if (lane == 0) {
        float bu = snll * (1.f / 64.f);
        float hp = shpc > 0.f ? shps / shpc : 0.f;
        float hn = shnc > 0.f ? shns / shnc : 0.f;
        out[0] = bu + hp + hn;
    }
}

extern "C" void kernel_launch(void* const* d_in, const int* in_sizes, int n_in,
                              void* d_out, int out_size, void* d_ws, size_t ws_size,
                              hipStream_t stream) {
    const float* inputs = (const float*)d_in[0];
    const int* targets  = (const int*)d_in[1];
    const void* pmask   = d_in[2];
    const void* nmask   = d_in[3];
    const float* V      = (const float*)d_in[4];
    float* out = (float*)d_out;      // out[0] = loss
    float* logits = out + 1;         // out[1..] = logits [64][100000] row-major
    float* ws = (float*)d_ws;        // [GBLK*64] exp partials | [64*64] Gram

    hipLaunchKernelGGL(k_gemm, dim3(GBLK + 1), dim3(256), 0, stream,
                       inputs, V, logits, ws);
    hipLaunchKernelGGL(k_final, dim3(1), dim3(256), 0, stream,
                       targets, pmask, nmask, logits, ws, out);
}